// Round 5
// baseline (289.237 us; speedup 1.0000x reference)
//
#include <hip/hip_runtime.h>

#define NNODES 8192
#define NFEAT  128
#define NHID   32
#define NMETA  3
#define NCLASS 16
#define ALPHA  0.2f
#define KSPLIT 4
#define KRANGE (NNODES / KSPLIT)   // 2048 (pass-2 k-split)
#define BK     256                 // pass-1 k-tile (f32)
#define NT     (NNODES / BK)       // 32 tiles

typedef __attribute__((ext_vector_type(4))) float        f32x4;
typedef __attribute__((ext_vector_type(8))) __bf16       bf16x8;
typedef __attribute__((ext_vector_type(4))) __bf16       bf16x4;
typedef __attribute__((ext_vector_type(2))) unsigned int u32x2;

// A8 fragment layout: A8[m][frag=u/16][kb=k/32][lane][8B]
#define A8_FRAGS_PER_M   (NNODES / 16)            // 512
#define A8_KBLKS         (NNODES / 32)            // 256
__device__ __forceinline__ size_t a8_off(int m, int frag, int kb, int lane) {
    return ((((size_t)m * A8_FRAGS_PER_M + frag) * A8_KBLKS + kb) * 64 + lane) * 8;
}

// ---------------------------------------------------------------------------
// Kernel 1: Btf = fragment-major bf16 of (x @ W1)^T.
// ---------------------------------------------------------------------------
__global__ __launch_bounds__(256)
void k_xw(const float* __restrict__ x, const float* __restrict__ W1,
          __bf16* __restrict__ Btf)
{
    __shared__ float w[NFEAT * NHID];
    const int m = blockIdx.y, t = threadIdx.x;
    for (int idx = t; idx < NFEAT * NHID; idx += 256)
        w[idx] = W1[m * NFEAT * NHID + idx];
    __syncthreads();

    const int v = blockIdx.x * 256 + t;
    float acc[NHID];
#pragma unroll
    for (int h = 0; h < NHID; ++h) acc[h] = 0.f;
    const f32x4* xr = (const f32x4*)(x + (size_t)v * NFEAT);
    for (int f4 = 0; f4 < NFEAT / 4; ++f4) {
        f32x4 xv = xr[f4];
#pragma unroll
        for (int ff = 0; ff < 4; ++ff) {
            float xs = xv[ff];
#pragma unroll
            for (int h = 0; h < NHID; ++h)
                acc[h] += xs * w[(f4 * 4 + ff) * NHID + h];
        }
    }
    const int kb = v >> 5, q = v & 31, kg = q >> 3, j = q & 7;
    __bf16* base = Btf + ((size_t)m * A8_KBLKS + kb) * 1024;
#pragma unroll
    for (int c = 0; c < NHID; ++c) {
        const int cgrp = c >> 4;
        const int lane = kg * 16 + (c & 15);
        base[(cgrp * 64 + lane) * 8 + j] = (__bf16)acc[c];
    }
}

// ---------------------------------------------------------------------------
// Kernel 2: pass-1 spmm. LDS-staged contiguous NT reads, now with a TWO-TILE
// register prefetch pipeline (stA/stB) so the stage-wait never sees raw HBM
// latency — only true BW limits.
// ---------------------------------------------------------------------------
__global__ __launch_bounds__(256, 3)
void k_spmm1(const float* __restrict__ adj, const __bf16* __restrict__ Btf,
             const float* __restrict__ b1, unsigned char* __restrict__ A8,
             __bf16* __restrict__ h1)
{
    __shared__ __align__(16) __bf16 lds[2 * 32 * BK];   // 2 x 16 KB
    const int tid  = threadIdx.x;
    const int lane = tid & 63;
    const int w    = tid >> 6;
    const int ln15 = lane & 15;
    const int kg   = lane >> 4;
    const int bx   = blockIdx.x;
    const int m    = blockIdx.y;
    const int u0   = bx * 32;

    const float*  Arow = adj + (size_t)m * NNODES * NNODES
                             + (size_t)(u0 + w * 8) * NNODES;
    const __bf16* Bb   = Btf + (size_t)m * A8_KBLKS * 1024;

    f32x4 acc00 = {0.f,0.f,0.f,0.f}, acc01 = {0.f,0.f,0.f,0.f};
    f32x4 acc10 = {0.f,0.f,0.f,0.f}, acc11 = {0.f,0.f,0.f,0.f};

    f32x4 stA[8], stB[8];

    auto issue = [&](f32x4* st, int t) {
        const float* An = Arow + (size_t)t * BK;
#pragma unroll
        for (int rr = 0; rr < 8; ++rr)
            st[rr] = __builtin_nontemporal_load(
                (const f32x4*)(An + (size_t)rr * NNODES + lane * 4));
    };
    auto stage = [&](f32x4* st, int buf) {
#pragma unroll
        for (int rr = 0; rr < 8; ++rr) {
            const int row = w * 8 + rr;
            bf16x4 c4;
#pragma unroll
            for (int e = 0; e < 4; ++e) c4[e] = (__bf16)st[rr][e];
            const int idx = buf + row * BK + lane * 4;
            *(bf16x4*)(&lds[idx ^ (rr << 3)]) = c4;
        }
    };
    auto mfma_phase = [&](int buf, int t) {
#pragma unroll
        for (int kk = 0; kk < 2; ++kk) {
            const int klocal = w * 64 + kk * 32;
            const int kb     = t * 8 + w * 2 + kk;
            const int i0 = (buf + ln15 * BK + klocal + kg * 8) ^ ((ln15 & 7) << 3);
            const int i1 = (buf + (ln15 + 16) * BK + klocal + kg * 8) ^ ((ln15 & 7) << 3);
            bf16x8 a0 = *(const bf16x8*)(&lds[i0]);
            bf16x8 a1 = *(const bf16x8*)(&lds[i1]);
            bf16x8 b0 = *(const bf16x8*)(Bb + ((size_t)kb * 2 + 0) * 512 + lane * 8);
            bf16x8 b1f= *(const bf16x8*)(Bb + ((size_t)kb * 2 + 1) * 512 + lane * 8);
            acc00 = __builtin_amdgcn_mfma_f32_16x16x32_bf16(a0, b0, acc00, 0, 0, 0);
            acc01 = __builtin_amdgcn_mfma_f32_16x16x32_bf16(a0, b1f, acc01, 0, 0, 0);
            acc10 = __builtin_amdgcn_mfma_f32_16x16x32_bf16(a1, b0, acc10, 0, 0, 0);
            acc11 = __builtin_amdgcn_mfma_f32_16x16x32_bf16(a1, b1f, acc11, 0, 0, 0);

            const float S = 8192.0f;
            unsigned int p; u32x2 q;
            p = __builtin_amdgcn_cvt_pk_fp8_f32((float)a0[0]*S, (float)a0[1]*S, 0u, false);
            p = __builtin_amdgcn_cvt_pk_fp8_f32((float)a0[2]*S, (float)a0[3]*S, p,  true);
            q.x = p;
            p = __builtin_amdgcn_cvt_pk_fp8_f32((float)a0[4]*S, (float)a0[5]*S, 0u, false);
            p = __builtin_amdgcn_cvt_pk_fp8_f32((float)a0[6]*S, (float)a0[7]*S, p,  true);
            q.y = p;
            *(u32x2*)(A8 + a8_off(m, bx * 2 + 0, kb, lane)) = q;
            p = __builtin_amdgcn_cvt_pk_fp8_f32((float)a1[0]*S, (float)a1[1]*S, 0u, false);
            p = __builtin_amdgcn_cvt_pk_fp8_f32((float)a1[2]*S, (float)a1[3]*S, p,  true);
            q.x = p;
            p = __builtin_amdgcn_cvt_pk_fp8_f32((float)a1[4]*S, (float)a1[5]*S, 0u, false);
            p = __builtin_amdgcn_cvt_pk_fp8_f32((float)a1[6]*S, (float)a1[7]*S, p,  true);
            q.y = p;
            *(u32x2*)(A8 + a8_off(m, bx * 2 + 1, kb, lane)) = q;
        }
    };

    // prologue: two tiles in flight
    issue(stA, 0);
    issue(stB, 1);

    for (int t = 0; t < NT; t += 2) {
        stage(stA, 0);                 // waits only on stA's loads (t)
        __syncthreads();
        if (t + 2 < NT) issue(stA, t + 2);
        mfma_phase(0, t);

        stage(stB, 32 * BK);           // waits only on stB's loads (t+1)
        __syncthreads();
        if (t + 3 < NT) issue(stB, t + 3);
        mfma_phase(32 * BK, t + 1);
    }

    __syncthreads();
    float* red = (float*)lds;
#pragma unroll
    for (int i = 0; i < 2; ++i)
#pragma unroll
        for (int j = 0; j < 2; ++j) {
            f32x4 acc = (i == 0) ? (j == 0 ? acc00 : acc01)
                                 : (j == 0 ? acc10 : acc11);
            const int c = 16 * j + ln15;
#pragma unroll
            for (int e = 0; e < 4; ++e) {
                const int u = 16 * i + 4 * kg + e;
                red[(w * 1024) + u * 32 + c] = acc[e];
            }
        }
    __syncthreads();

    {
        const int u  = tid >> 3;
        const int c0 = (tid & 7) * 4;
        f32x4 s = *(const f32x4*)(&red[u * 32 + c0]);
#pragma unroll
        for (int ww = 1; ww < 4; ++ww)
            s += *(const f32x4*)(&red[ww * 1024 + u * 32 + c0]);
        bf16x4 o4;
#pragma unroll
        for (int e = 0; e < 4; ++e) {
            float val = s[e] + b1[m * NHID + c0 + e];
            o4[e] = (__bf16)(val > 0.f ? val : 0.f);
        }
        *(bf16x4*)(h1 + ((size_t)m * NNODES + u0 + u) * NHID + c0) = o4;
    }
}

// ---------------------------------------------------------------------------
// Kernel 3: T2t8[m][d][v] = fp8(64 * (h1[m][v][:] @ W2[m]))
// ---------------------------------------------------------------------------
__global__ __launch_bounds__(256)
void k_hw(const __bf16* __restrict__ h1, const float* __restrict__ W2,
          unsigned char* __restrict__ T2t8)
{
    __shared__ float w[NHID * NHID];
    const int m = blockIdx.y, t = threadIdx.x;
    for (int idx = t; idx < NHID * NHID; idx += 256)
        w[idx] = W2[m * NHID * NHID + idx];
    __syncthreads();

    const int v = blockIdx.x * 256 + t;
    const __bf16* hr = h1 + ((size_t)m * NNODES + v) * NHID;
    float h[NHID];
#pragma unroll
    for (int i = 0; i < 4; ++i) {
        bf16x8 hb = *(const bf16x8*)(hr + i * 8);
#pragma unroll
        for (int e = 0; e < 8; ++e) h[i * 8 + e] = (float)hb[e];
    }

    float acc[NHID];
#pragma unroll
    for (int d = 0; d < NHID; ++d) acc[d] = 0.f;
    for (int hh = 0; hh < NHID; ++hh) {
        const float hs = h[hh];
#pragma unroll
        for (int d = 0; d < NHID; ++d) acc[d] += hs * w[hh * NHID + d];
    }
#pragma unroll
    for (int d = 0; d < NHID; ++d) {
        unsigned int p = __builtin_amdgcn_cvt_pk_fp8_f32(acc[d] * 64.0f, 0.f, 0u, false);
        T2t8[((size_t)m * NHID + d) * NNODES + v] = (unsigned char)(p & 0xff);
    }
}

// ---------------------------------------------------------------------------
// Kernel 4: pass-2 spmm (fp8 MFMA on A8 frags + T2t8) -> h2p4 partials
// ---------------------------------------------------------------------------
__global__ __launch_bounds__(64)
void k_spmm2(const unsigned char* __restrict__ A8,
             const unsigned char* __restrict__ T2t8,
             float* __restrict__ h2p4)
{
    const int lane = threadIdx.x;
    const int ln15 = lane & 15;
    const int kg   = lane >> 4;
    const int bx   = blockIdx.x;
    const int kz   = blockIdx.y;
    const int m    = blockIdx.z;
    const int u0   = bx * 32;
    const int kbeg = kz * KRANGE;

    const long* A8f0 = (const long*)(A8 + a8_off(m, bx * 2 + 0, 0, lane));
    const long* A8f1 = (const long*)(A8 + a8_off(m, bx * 2 + 1, 0, lane));
    const unsigned char* B0 = T2t8 + (size_t)m * NHID * NNODES
                                   + (size_t)ln15 * NNODES + kg * 8;
    const unsigned char* B1 = B0 + (size_t)16 * NNODES;

    f32x4 acc00 = {0.f,0.f,0.f,0.f}, acc01 = {0.f,0.f,0.f,0.f};
    f32x4 acc10 = {0.f,0.f,0.f,0.f}, acc11 = {0.f,0.f,0.f,0.f};

    for (int k0 = kbeg; k0 < kbeg + KRANGE; k0 += 256) {
#pragma unroll
        for (int kk = 0; kk < 8; ++kk) {
            const int k  = k0 + kk * 32;
            const int kb = k >> 5;
            long a0 = A8f0[(size_t)kb * 64];
            long a1 = A8f1[(size_t)kb * 64];
            long b0 = *(const long*)(B0 + k);
            long b1 = *(const long*)(B1 + k);
            acc00 = __builtin_amdgcn_mfma_f32_16x16x32_fp8_fp8(a0, b0, acc00, 0, 0, 0);
            acc01 = __builtin_amdgcn_mfma_f32_16x16x32_fp8_fp8(a0, b1, acc01, 0, 0, 0);
            acc10 = __builtin_amdgcn_mfma_f32_16x16x32_fp8_fp8(a1, b0, acc10, 0, 0, 0);
            acc11 = __builtin_amdgcn_mfma_f32_16x16x32_fp8_fp8(a1, b1, acc11, 0, 0, 0);
        }
    }

    const float INV = 1.0f / (8192.0f * 64.0f);
    float* hp = h2p4 + (((size_t)kz * NMETA + m) * NNODES) * NHID;
#pragma unroll
    for (int i = 0; i < 2; ++i)
#pragma unroll
        for (int j = 0; j < 2; ++j) {
            f32x4 acc = (i == 0) ? (j == 0 ? acc00 : acc01)
                                 : (j == 0 ? acc10 : acc11);
            const int c = 16 * j + ln15;
#pragma unroll
            for (int e = 0; e < 4; ++e) {
                const int u = u0 + 16 * i + 4 * kg + e;
                hp[(size_t)u * NHID + c] = acc[e] * INV;
            }
        }
}

// ---------------------------------------------------------------------------
// Kernel 5a: wide reduce  h2[m][n][:] = relu(sum_kz h2p4 + b2)
// ---------------------------------------------------------------------------
__global__ __launch_bounds__(256)
void k_red(const float* __restrict__ h2p4, const float* __restrict__ b2,
           float* __restrict__ h2)
{
    const int tid = blockIdx.x * 256 + threadIdx.x;
    const int d4  = tid & 7;
    const int nm  = tid >> 3;
    const int n   = nm & (NNODES - 1);
    const int m   = nm >> 13;

    f32x4 s = {0.f,0.f,0.f,0.f};
#pragma unroll
    for (int kz = 0; kz < KSPLIT; ++kz)
        s += *(const f32x4*)(h2p4 +
            (((size_t)kz * NMETA + m) * NNODES + n) * NHID + d4 * 4);

    f32x4 o;
#pragma unroll
    for (int e = 0; e < 4; ++e) {
        float val = s[e] + b2[m * NHID + d4 * 4 + e];
        o[e] = val > 0.f ? val : 0.f;
    }
    *(f32x4*)(h2 + ((size_t)m * NNODES + n) * NHID + d4 * 4) = o;
}

// ---------------------------------------------------------------------------
// Kernel 5b: attention + linear + log_softmax  (128 blocks x 64 thr)
// ---------------------------------------------------------------------------
__global__ __launch_bounds__(64)
void k_final(const float* __restrict__ h2, const float* __restrict__ a,
             const float* __restrict__ Wl, const float* __restrict__ bl,
             float* __restrict__ out)
{
    __shared__ float ws_a[NHID];
    __shared__ float ws_w[NHID * NCLASS];
    __shared__ float ws_b[NCLASS];
    const int t = threadIdx.x;
    if (t < NHID) ws_a[t] = a[t];
    for (int idx = t; idx < NHID * NCLASS; idx += 64) ws_w[idx] = Wl[idx];
    if (t < NCLASS) ws_b[t] = bl[t];
    __syncthreads();

    const int n = blockIdx.x * 64 + t;

    float hv[NMETA][NHID];
#pragma unroll
    for (int m = 0; m < NMETA; ++m) {
        const f32x4* hp = (const f32x4*)(h2 + ((size_t)m * NNODES + n) * NHID);
#pragma unroll
        for (int d4 = 0; d4 < NHID / 4; ++d4) {
            f32x4 v = hp[d4];
#pragma unroll
            for (int e = 0; e < 4; ++e) hv[m][d4 * 4 + e] = v[e];
        }
    }

    float em[NMETA];
#pragma unroll
    for (int m = 0; m < NMETA; ++m) {
        float d = 0.f;
#pragma unroll
        for (int h = 0; h < NHID; ++h) d += hv[m][h] * ws_a[h];
        em[m] = d > 0.f ? d : ALPHA * d;
    }

    float mx = fmaxf(em[0], fmaxf(em[1], em[2]));
    float w0 = __expf(em[0] - mx), w1 = __expf(em[1] - mx), w2 = __expf(em[2] - mx);
    float inv = 1.f / (w0 + w1 + w2);
    w0 *= inv; w1 *= inv; w2 *= inv;

    float o[NHID];
#pragma unroll
    for (int d = 0; d < NHID; ++d)
        o[d] = w0 * hv[0][d] + w1 * hv[1][d] + w2 * hv[2][d];

    float lg[NCLASS];
#pragma unroll
    for (int c = 0; c < NCLASS; ++c) lg[c] = ws_b[c];
    for (int d = 0; d < NHID; ++d) {
        const float od = o[d];
#pragma unroll
        for (int c = 0; c < NCLASS; ++c) lg[c] += od * ws_w[d * NCLASS + c];
    }
#pragma unroll
    for (int c = 0; c < NCLASS; ++c) lg[c] = lg[c] > 0.f ? lg[c] : 0.f;

    float lmx = lg[0];
#pragma unroll
    for (int c = 1; c < NCLASS; ++c) lmx = fmaxf(lmx, lg[c]);
    float ls = 0.f;
#pragma unroll
    for (int c = 0; c < NCLASS; ++c) ls += __expf(lg[c] - lmx);
    const float lse = lmx + __logf(ls);
#pragma unroll
    for (int c = 0; c < NCLASS; ++c)
        out[(size_t)n * NCLASS + c] = lg[c] - lse;
}

// ---------------------------------------------------------------------------
extern "C" void kernel_launch(void* const* d_in, const int* in_sizes, int n_in,
                              void* d_out, int out_size, void* d_ws, size_t ws_size,
                              hipStream_t stream) {
    const float* x    = (const float*)d_in[0];
    const float* adjs = (const float*)d_in[1];
    const float* W1   = (const float*)d_in[2];
    const float* b1   = (const float*)d_in[3];
    const float* W2   = (const float*)d_in[4];
    const float* b2   = (const float*)d_in[5];
    const float* a    = (const float*)d_in[6];
    const float* Wl   = (const float*)d_in[7];
    const float* bl   = (const float*)d_in[8];
    float* out = (float*)d_out;

    char* ws = (char*)d_ws;
    // layout: Btf 1.5MB @0 | T2t8 0.75MB @2MB | h1 1.5MB @3MB |
    //         h2 3MB @8MB | h2p4 12.6MB @16MB | A8 201.3MB @32MB
    __bf16*        Btf  = (__bf16*)(ws);
    unsigned char* T2t8 = (unsigned char*)(ws + (2ull  << 20));
    __bf16*        h1   = (__bf16*)       (ws + (3ull  << 20));
    float*         h2   = (float*)        (ws + (8ull  << 20));
    float*         h2p4 = (float*)        (ws + (16ull << 20));
    unsigned char* A8   = (unsigned char*)(ws + (32ull << 20));

    dim3 gsmall(NNODES / 256, NMETA);

    k_xw   <<<gsmall, 256, 0, stream>>>(x, W1, Btf);
    k_spmm1<<<dim3(NNODES / 32, NMETA), 256, 0, stream>>>(adjs, Btf, b1, A8, h1);
    k_hw   <<<gsmall, 256, 0, stream>>>(h1, W2, T2t8);
    k_spmm2<<<dim3(NNODES / 32, KSPLIT, NMETA), 64, 0, stream>>>(A8, T2t8, h2p4);
    k_red  <<<NMETA * NNODES * 8 / 256, 256, 0, stream>>>(h2p4, b2, h2);
    k_final<<<NNODES / 64, 64, 0, stream>>>(h2, a, Wl, bl, out);
}

// Round 6
// 268.932 us; speedup vs baseline: 1.0755x; 1.0755x over previous
//
#include <hip/hip_runtime.h>

#define NNODES 8192
#define NFEAT  128
#define NHID   32
#define NMETA  3
#define NCLASS 16
#define ALPHA  0.2f
#define KSPLIT 4
#define KRANGE (NNODES / KSPLIT)   // 2048 (pass-2 k-split)
#define BK     256                 // pass-1 k-tile (f32)
#define NT     (NNODES / BK)       // 32 tiles

typedef __attribute__((ext_vector_type(4))) float        f32x4;
typedef __attribute__((ext_vector_type(8))) __bf16       bf16x8;
typedef __attribute__((ext_vector_type(4))) __bf16       bf16x4;
typedef __attribute__((ext_vector_type(2))) unsigned int u32x2;

// A4 (u4-packed adj*8192*15) fragment layout: A4[m][frag=u/16][kb=k/32][lane][4B]
// nibble i of the u32 = element k = kg*8 + i (same per-lane order as fp8 frags).
#define A_FRAGS_PER_M   (NNODES / 16)            // 512
#define A_KBLKS         (NNODES / 32)            // 256
__device__ __forceinline__ size_t a4_off(int m, int frag, int kb, int lane) {
    return ((((size_t)m * A_FRAGS_PER_M + frag) * A_KBLKS + kb) * 64 + lane) * 4;
}

// pack 8 bf16 adj values -> 8 u4 nibbles (scale 8192*15, RNE via 2^23 magic)
__device__ __forceinline__ unsigned int pack_u4(const bf16x8& a) {
    unsigned int w = 0;
#pragma unroll
    for (int i = 0; i < 8; ++i) {
        float fv = fmaf((float)a[i], 122880.0f, 8388608.0f);  // 2^23 + n, RNE
        unsigned int n = __float_as_uint(fv) & 0xFu;
        w |= n << (4 * i);
    }
    return w;
}

// expand 8 u4 nibbles -> 8 fp8(e4m3) bytes encoding exact integers 0..15
__device__ __forceinline__ long expand_u4(unsigned int w) {
    float f[8];
#pragma unroll
    for (int i = 0; i < 8; ++i)
        f[i] = (float)((w >> (4 * i)) & 0xFu);
    unsigned int x, y;
    x = __builtin_amdgcn_cvt_pk_fp8_f32(f[0], f[1], 0u, false);
    x = __builtin_amdgcn_cvt_pk_fp8_f32(f[2], f[3], x,  true);
    y = __builtin_amdgcn_cvt_pk_fp8_f32(f[4], f[5], 0u, false);
    y = __builtin_amdgcn_cvt_pk_fp8_f32(f[6], f[7], y,  true);
    return (long)(((unsigned long long)y << 32) | x);
}

// ---------------------------------------------------------------------------
// Kernel 1: Btf = fragment-major bf16 of (x @ W1)^T.
// ---------------------------------------------------------------------------
__global__ __launch_bounds__(256)
void k_xw(const float* __restrict__ x, const float* __restrict__ W1,
          __bf16* __restrict__ Btf)
{
    __shared__ float w[NFEAT * NHID];
    const int m = blockIdx.y, t = threadIdx.x;
    for (int idx = t; idx < NFEAT * NHID; idx += 256)
        w[idx] = W1[m * NFEAT * NHID + idx];
    __syncthreads();

    const int v = blockIdx.x * 256 + t;
    float acc[NHID];
#pragma unroll
    for (int h = 0; h < NHID; ++h) acc[h] = 0.f;
    const f32x4* xr = (const f32x4*)(x + (size_t)v * NFEAT);
    for (int f4 = 0; f4 < NFEAT / 4; ++f4) {
        f32x4 xv = xr[f4];
#pragma unroll
        for (int ff = 0; ff < 4; ++ff) {
            float xs = xv[ff];
#pragma unroll
            for (int h = 0; h < NHID; ++h)
                acc[h] += xs * w[(f4 * 4 + ff) * NHID + h];
        }
    }
    const int kb = v >> 5, q = v & 31, kg = q >> 3, j = q & 7;
    __bf16* base = Btf + ((size_t)m * A_KBLKS + kb) * 1024;
#pragma unroll
    for (int c = 0; c < NHID; ++c) {
        const int cgrp = c >> 4;
        const int lane = kg * 16 + (c & 15);
        base[(cgrp * 64 + lane) * 8 + j] = (__bf16)acc[c];
    }
}

// ---------------------------------------------------------------------------
// Kernel 2: pass-1 spmm. LDS-staged contiguous NT reads, 2-tile reg prefetch,
// bf16 MFMA vs Btf; side-writes u4-packed adj fragments (A4) for pass 2.
// ---------------------------------------------------------------------------
__global__ __launch_bounds__(256, 3)
void k_spmm1(const float* __restrict__ adj, const __bf16* __restrict__ Btf,
             const float* __restrict__ b1, unsigned int* __restrict__ A4,
             __bf16* __restrict__ h1)
{
    __shared__ __align__(16) __bf16 lds[2 * 32 * BK];   // 2 x 16 KB
    const int tid  = threadIdx.x;
    const int lane = tid & 63;
    const int w    = tid >> 6;
    const int ln15 = lane & 15;
    const int kg   = lane >> 4;
    const int bx   = blockIdx.x;
    const int m    = blockIdx.y;
    const int u0   = bx * 32;

    const float*  Arow = adj + (size_t)m * NNODES * NNODES
                             + (size_t)(u0 + w * 8) * NNODES;
    const __bf16* Bb   = Btf + (size_t)m * A_KBLKS * 1024;

    f32x4 acc00 = {0.f,0.f,0.f,0.f}, acc01 = {0.f,0.f,0.f,0.f};
    f32x4 acc10 = {0.f,0.f,0.f,0.f}, acc11 = {0.f,0.f,0.f,0.f};

    f32x4 stA[8], stB[8];

    auto issue = [&](f32x4* st, int t) {
        const float* An = Arow + (size_t)t * BK;
#pragma unroll
        for (int rr = 0; rr < 8; ++rr)
            st[rr] = __builtin_nontemporal_load(
                (const f32x4*)(An + (size_t)rr * NNODES + lane * 4));
    };
    auto stage = [&](f32x4* st, int buf) {
#pragma unroll
        for (int rr = 0; rr < 8; ++rr) {
            const int row = w * 8 + rr;
            bf16x4 c4;
#pragma unroll
            for (int e = 0; e < 4; ++e) c4[e] = (__bf16)st[rr][e];
            const int idx = buf + row * BK + lane * 4;
            *(bf16x4*)(&lds[idx ^ (rr << 3)]) = c4;
        }
    };
    auto mfma_phase = [&](int buf, int t) {
#pragma unroll
        for (int kk = 0; kk < 2; ++kk) {
            const int klocal = w * 64 + kk * 32;
            const int kb     = t * 8 + w * 2 + kk;
            const int i0 = (buf + ln15 * BK + klocal + kg * 8) ^ ((ln15 & 7) << 3);
            const int i1 = (buf + (ln15 + 16) * BK + klocal + kg * 8) ^ ((ln15 & 7) << 3);
            bf16x8 a0 = *(const bf16x8*)(&lds[i0]);
            bf16x8 a1 = *(const bf16x8*)(&lds[i1]);
            bf16x8 b0 = *(const bf16x8*)(Bb + ((size_t)kb * 2 + 0) * 512 + lane * 8);
            bf16x8 b1f= *(const bf16x8*)(Bb + ((size_t)kb * 2 + 1) * 512 + lane * 8);
            acc00 = __builtin_amdgcn_mfma_f32_16x16x32_bf16(a0, b0, acc00, 0, 0, 0);
            acc01 = __builtin_amdgcn_mfma_f32_16x16x32_bf16(a0, b1f, acc01, 0, 0, 0);
            acc10 = __builtin_amdgcn_mfma_f32_16x16x32_bf16(a1, b0, acc10, 0, 0, 0);
            acc11 = __builtin_amdgcn_mfma_f32_16x16x32_bf16(a1, b1f, acc11, 0, 0, 0);

            // u4(adj*8192*15) fragment side-write for pass 2
            A4[a4_off(m, bx * 2 + 0, kb, lane) >> 2] = pack_u4(a0);
            A4[a4_off(m, bx * 2 + 1, kb, lane) >> 2] = pack_u4(a1);
        }
    };

    issue(stA, 0);
    issue(stB, 1);

    for (int t = 0; t < NT; t += 2) {
        stage(stA, 0);
        __syncthreads();
        if (t + 2 < NT) issue(stA, t + 2);
        mfma_phase(0, t);

        stage(stB, 32 * BK);
        __syncthreads();
        if (t + 3 < NT) issue(stB, t + 3);
        mfma_phase(32 * BK, t + 1);
    }

    __syncthreads();
    float* red = (float*)lds;
#pragma unroll
    for (int i = 0; i < 2; ++i)
#pragma unroll
        for (int j = 0; j < 2; ++j) {
            f32x4 acc = (i == 0) ? (j == 0 ? acc00 : acc01)
                                 : (j == 0 ? acc10 : acc11);
            const int c = 16 * j + ln15;
#pragma unroll
            for (int e = 0; e < 4; ++e) {
                const int u = 16 * i + 4 * kg + e;
                red[(w * 1024) + u * 32 + c] = acc[e];
            }
        }
    __syncthreads();

    {
        const int u  = tid >> 3;
        const int c0 = (tid & 7) * 4;
        f32x4 s = *(const f32x4*)(&red[u * 32 + c0]);
#pragma unroll
        for (int ww = 1; ww < 4; ++ww)
            s += *(const f32x4*)(&red[ww * 1024 + u * 32 + c0]);
        bf16x4 o4;
#pragma unroll
        for (int e = 0; e < 4; ++e) {
            float val = s[e] + b1[m * NHID + c0 + e];
            o4[e] = (__bf16)(val > 0.f ? val : 0.f);
        }
        *(bf16x4*)(h1 + ((size_t)m * NNODES + u0 + u) * NHID + c0) = o4;
    }
}

// ---------------------------------------------------------------------------
// Kernel 3: T2t8[m][d][v] = fp8(64 * (h1[m][v][:] @ W2[m]))
// ---------------------------------------------------------------------------
__global__ __launch_bounds__(256)
void k_hw(const __bf16* __restrict__ h1, const float* __restrict__ W2,
          unsigned char* __restrict__ T2t8)
{
    __shared__ float w[NHID * NHID];
    const int m = blockIdx.y, t = threadIdx.x;
    for (int idx = t; idx < NHID * NHID; idx += 256)
        w[idx] = W2[m * NHID * NHID + idx];
    __syncthreads();

    const int v = blockIdx.x * 256 + t;
    const __bf16* hr = h1 + ((size_t)m * NNODES + v) * NHID;
    float h[NHID];
#pragma unroll
    for (int i = 0; i < 4; ++i) {
        bf16x8 hb = *(const bf16x8*)(hr + i * 8);
#pragma unroll
        for (int e = 0; e < 8; ++e) h[i * 8 + e] = (float)hb[e];
    }

    float acc[NHID];
#pragma unroll
    for (int d = 0; d < NHID; ++d) acc[d] = 0.f;
    for (int hh = 0; hh < NHID; ++hh) {
        const float hs = h[hh];
#pragma unroll
        for (int d = 0; d < NHID; ++d) acc[d] += hs * w[hh * NHID + d];
    }
#pragma unroll
    for (int d = 0; d < NHID; ++d) {
        unsigned int p = __builtin_amdgcn_cvt_pk_fp8_f32(acc[d] * 64.0f, 0.f, 0u, false);
        T2t8[((size_t)m * NHID + d) * NNODES + v] = (unsigned char)(p & 0xff);
    }
}

// ---------------------------------------------------------------------------
// Kernel 4: pass-2 spmm: u4 A-frags expanded to fp8 in-register + fp8 B
// ---------------------------------------------------------------------------
__global__ __launch_bounds__(64)
void k_spmm2(const unsigned int* __restrict__ A4,
             const unsigned char* __restrict__ T2t8,
             float* __restrict__ h2p4)
{
    const int lane = threadIdx.x;
    const int ln15 = lane & 15;
    const int kg   = lane >> 4;
    const int bx   = blockIdx.x;
    const int kz   = blockIdx.y;
    const int m    = blockIdx.z;
    const int u0   = bx * 32;
    const int kbeg = kz * KRANGE;

    const unsigned int* A4f0 = A4 + (a4_off(m, bx * 2 + 0, 0, lane) >> 2);
    const unsigned int* A4f1 = A4 + (a4_off(m, bx * 2 + 1, 0, lane) >> 2);
    const unsigned char* B0 = T2t8 + (size_t)m * NHID * NNODES
                                   + (size_t)ln15 * NNODES + kg * 8;
    const unsigned char* B1 = B0 + (size_t)16 * NNODES;

    f32x4 acc00 = {0.f,0.f,0.f,0.f}, acc01 = {0.f,0.f,0.f,0.f};
    f32x4 acc10 = {0.f,0.f,0.f,0.f}, acc11 = {0.f,0.f,0.f,0.f};

    for (int k0 = kbeg; k0 < kbeg + KRANGE; k0 += 256) {
#pragma unroll
        for (int kk = 0; kk < 8; ++kk) {
            const int k  = k0 + kk * 32;
            const int kb = k >> 5;
            unsigned int w0 = A4f0[(size_t)kb * 64];
            unsigned int w1 = A4f1[(size_t)kb * 64];
            long a0 = expand_u4(w0);
            long a1 = expand_u4(w1);
            long b0 = *(const long*)(B0 + k);
            long b1 = *(const long*)(B1 + k);
            acc00 = __builtin_amdgcn_mfma_f32_16x16x32_fp8_fp8(a0, b0, acc00, 0, 0, 0);
            acc01 = __builtin_amdgcn_mfma_f32_16x16x32_fp8_fp8(a0, b1, acc01, 0, 0, 0);
            acc10 = __builtin_amdgcn_mfma_f32_16x16x32_fp8_fp8(a1, b0, acc10, 0, 0, 0);
            acc11 = __builtin_amdgcn_mfma_f32_16x16x32_fp8_fp8(a1, b1, acc11, 0, 0, 0);
        }
    }

    const float INV = 1.0f / (122880.0f * 64.0f);   // undo u4 and fp8-B scales
    float* hp = h2p4 + (((size_t)kz * NMETA + m) * NNODES) * NHID;
#pragma unroll
    for (int i = 0; i < 2; ++i)
#pragma unroll
        for (int j = 0; j < 2; ++j) {
            f32x4 acc = (i == 0) ? (j == 0 ? acc00 : acc01)
                                 : (j == 0 ? acc10 : acc11);
            const int c = 16 * j + ln15;
#pragma unroll
            for (int e = 0; e < 4; ++e) {
                const int u = u0 + 16 * i + 4 * kg + e;
                hp[(size_t)u * NHID + c] = acc[e] * INV;
            }
        }
}

// ---------------------------------------------------------------------------
// Kernel 5a: wide reduce  h2[m][n][:] = relu(sum_kz h2p4 + b2)
// ---------------------------------------------------------------------------
__global__ __launch_bounds__(256)
void k_red(const float* __restrict__ h2p4, const float* __restrict__ b2,
           float* __restrict__ h2)
{
    const int tid = blockIdx.x * 256 + threadIdx.x;
    const int d4  = tid & 7;
    const int nm  = tid >> 3;
    const int n   = nm & (NNODES - 1);
    const int m   = nm >> 13;

    f32x4 s = {0.f,0.f,0.f,0.f};
#pragma unroll
    for (int kz = 0; kz < KSPLIT; ++kz)
        s += *(const f32x4*)(h2p4 +
            (((size_t)kz * NMETA + m) * NNODES + n) * NHID + d4 * 4);

    f32x4 o;
#pragma unroll
    for (int e = 0; e < 4; ++e) {
        float val = s[e] + b2[m * NHID + d4 * 4 + e];
        o[e] = val > 0.f ? val : 0.f;
    }
    *(f32x4*)(h2 + ((size_t)m * NNODES + n) * NHID + d4 * 4) = o;
}

// ---------------------------------------------------------------------------
// Kernel 5b: attention + linear + log_softmax  (128 blocks x 64 thr)
// ---------------------------------------------------------------------------
__global__ __launch_bounds__(64)
void k_final(const float* __restrict__ h2, const float* __restrict__ a,
             const float* __restrict__ Wl, const float* __restrict__ bl,
             float* __restrict__ out)
{
    __shared__ float ws_a[NHID];
    __shared__ float ws_w[NHID * NCLASS];
    __shared__ float ws_b[NCLASS];
    const int t = threadIdx.x;
    if (t < NHID) ws_a[t] = a[t];
    for (int idx = t; idx < NHID * NCLASS; idx += 64) ws_w[idx] = Wl[idx];
    if (t < NCLASS) ws_b[t] = bl[t];
    __syncthreads();

    const int n = blockIdx.x * 64 + t;

    float hv[NMETA][NHID];
#pragma unroll
    for (int m = 0; m < NMETA; ++m) {
        const f32x4* hp = (const f32x4*)(h2 + ((size_t)m * NNODES + n) * NHID);
#pragma unroll
        for (int d4 = 0; d4 < NHID / 4; ++d4) {
            f32x4 v = hp[d4];
#pragma unroll
            for (int e = 0; e < 4; ++e) hv[m][d4 * 4 + e] = v[e];
        }
    }

    float em[NMETA];
#pragma unroll
    for (int m = 0; m < NMETA; ++m) {
        float d = 0.f;
#pragma unroll
        for (int h = 0; h < NHID; ++h) d += hv[m][h] * ws_a[h];
        em[m] = d > 0.f ? d : ALPHA * d;
    }

    float mx = fmaxf(em[0], fmaxf(em[1], em[2]));
    float w0 = __expf(em[0] - mx), w1 = __expf(em[1] - mx), w2 = __expf(em[2] - mx);
    float inv = 1.f / (w0 + w1 + w2);
    w0 *= inv; w1 *= inv; w2 *= inv;

    float o[NHID];
#pragma unroll
    for (int d = 0; d < NHID; ++d)
        o[d] = w0 * hv[0][d] + w1 * hv[1][d] + w2 * hv[2][d];

    float lg[NCLASS];
#pragma unroll
    for (int c = 0; c < NCLASS; ++c) lg[c] = ws_b[c];
    for (int d = 0; d < NHID; ++d) {
        const float od = o[d];
#pragma unroll
        for (int c = 0; c < NCLASS; ++c) lg[c] += od * ws_w[d * NCLASS + c];
    }
#pragma unroll
    for (int c = 0; c < NCLASS; ++c) lg[c] = lg[c] > 0.f ? lg[c] : 0.f;

    float lmx = lg[0];
#pragma unroll
    for (int c = 1; c < NCLASS; ++c) lmx = fmaxf(lmx, lg[c]);
    float ls = 0.f;
#pragma unroll
    for (int c = 0; c < NCLASS; ++c) ls += __expf(lg[c] - lmx);
    const float lse = lmx + __logf(ls);
#pragma unroll
    for (int c = 0; c < NCLASS; ++c)
        out[(size_t)n * NCLASS + c] = lg[c] - lse;
}

// ---------------------------------------------------------------------------
extern "C" void kernel_launch(void* const* d_in, const int* in_sizes, int n_in,
                              void* d_out, int out_size, void* d_ws, size_t ws_size,
                              hipStream_t stream) {
    const float* x    = (const float*)d_in[0];
    const float* adjs = (const float*)d_in[1];
    const float* W1   = (const float*)d_in[2];
    const float* b1   = (const float*)d_in[3];
    const float* W2   = (const float*)d_in[4];
    const float* b2   = (const float*)d_in[5];
    const float* a    = (const float*)d_in[6];
    const float* Wl   = (const float*)d_in[7];
    const float* bl   = (const float*)d_in[8];
    float* out = (float*)d_out;

    char* ws = (char*)d_ws;
    // layout: Btf 1.5MB @0 | T2t8 0.75MB @2MB | h1 1.5MB @3MB |
    //         h2 3MB @8MB | h2p4 12.6MB @16MB | A4 100.7MB @32MB
    __bf16*        Btf  = (__bf16*)(ws);
    unsigned char* T2t8 = (unsigned char*)(ws + (2ull  << 20));
    __bf16*        h1   = (__bf16*)       (ws + (3ull  << 20));
    float*         h2   = (float*)        (ws + (8ull  << 20));
    float*         h2p4 = (float*)        (ws + (16ull << 20));
    unsigned int*  A4   = (unsigned int*) (ws + (32ull << 20));

    dim3 gsmall(NNODES / 256, NMETA);

    k_xw   <<<gsmall, 256, 0, stream>>>(x, W1, Btf);
    k_spmm1<<<dim3(NNODES / 32, NMETA), 256, 0, stream>>>(adjs, Btf, b1, A4, h1);
    k_hw   <<<gsmall, 256, 0, stream>>>(h1, W2, T2t8);
    k_spmm2<<<dim3(NNODES / 32, KSPLIT, NMETA), 64, 0, stream>>>(A4, T2t8, h2p4);
    k_red  <<<NMETA * NNODES * 8 / 256, 256, 0, stream>>>(h2p4, b2, h2);
    k_final<<<NNODES / 64, 64, 0, stream>>>(h2, a, Wl, bl, out);
}

// Round 7
// 263.146 us; speedup vs baseline: 1.0992x; 1.0220x over previous
//
#include <hip/hip_runtime.h>

#define NNODES 8192
#define NFEAT  128
#define NHID   32
#define NMETA  3
#define NCLASS 16
#define ALPHA  0.2f
#define KSPLIT 4
#define KRANGE (NNODES / KSPLIT)   // 2048 (pass-2 k-split)
#define BK     256                 // pass-1 k-tile (f32)
#define NT     (NNODES / BK)       // 32 tiles

typedef __attribute__((ext_vector_type(4))) float        f32x4;
typedef __attribute__((ext_vector_type(8))) __bf16       bf16x8;
typedef __attribute__((ext_vector_type(4))) __bf16       bf16x4;
typedef __attribute__((ext_vector_type(2))) unsigned int u32x2;

// A4 (u4-packed adj*8192*15) fragment layout: A4[m][frag=u/16][kb=k/32][lane][4B]
#define A_FRAGS_PER_M   (NNODES / 16)            // 512
#define A_KBLKS         (NNODES / 32)            // 256
__device__ __forceinline__ size_t a4_off(int m, int frag, int kb, int lane) {
    return ((((size_t)m * A_FRAGS_PER_M + frag) * A_KBLKS + kb) * 64 + lane) * 4;
}

// pack 8 bf16 adj values -> 8 u4 nibbles (scale 8192*15, RNE via 2^23 magic)
__device__ __forceinline__ unsigned int pack_u4(const bf16x8& a) {
    unsigned int w = 0;
#pragma unroll
    for (int i = 0; i < 8; ++i) {
        float fv = fmaf((float)a[i], 122880.0f, 8388608.0f);  // 2^23 + n, RNE
        unsigned int n = __float_as_uint(fv) & 0xFu;
        w |= n << (4 * i);
    }
    return w;
}

// expand 8 u4 nibbles -> 8 fp8(e4m3) bytes encoding exact integers 0..15
__device__ __forceinline__ long expand_u4(unsigned int w) {
    float f[8];
#pragma unroll
    for (int i = 0; i < 8; ++i)
        f[i] = (float)((w >> (4 * i)) & 0xFu);
    unsigned int x, y;
    x = __builtin_amdgcn_cvt_pk_fp8_f32(f[0], f[1], 0u, false);
    x = __builtin_amdgcn_cvt_pk_fp8_f32(f[2], f[3], x,  true);
    y = __builtin_amdgcn_cvt_pk_fp8_f32(f[4], f[5], 0u, false);
    y = __builtin_amdgcn_cvt_pk_fp8_f32(f[6], f[7], y,  true);
    return (long)(((unsigned long long)y << 32) | x);
}

// ---------------------------------------------------------------------------
// Kernel 1: Btf = fragment-major bf16 of (x @ W1)^T.
// ---------------------------------------------------------------------------
__global__ __launch_bounds__(256)
void k_xw(const float* __restrict__ x, const float* __restrict__ W1,
          __bf16* __restrict__ Btf)
{
    __shared__ float w[NFEAT * NHID];
    const int m = blockIdx.y, t = threadIdx.x;
    for (int idx = t; idx < NFEAT * NHID; idx += 256)
        w[idx] = W1[m * NFEAT * NHID + idx];
    __syncthreads();

    const int v = blockIdx.x * 256 + t;
    float acc[NHID];
#pragma unroll
    for (int h = 0; h < NHID; ++h) acc[h] = 0.f;
    const f32x4* xr = (const f32x4*)(x + (size_t)v * NFEAT);
    for (int f4 = 0; f4 < NFEAT / 4; ++f4) {
        f32x4 xv = xr[f4];
#pragma unroll
        for (int ff = 0; ff < 4; ++ff) {
            float xs = xv[ff];
#pragma unroll
            for (int h = 0; h < NHID; ++h)
                acc[h] += xs * w[(f4 * 4 + ff) * NHID + h];
        }
    }
    const int kb = v >> 5, q = v & 31, kg = q >> 3, j = q & 7;
    __bf16* base = Btf + ((size_t)m * A_KBLKS + kb) * 1024;
#pragma unroll
    for (int c = 0; c < NHID; ++c) {
        const int cgrp = c >> 4;
        const int lane = kg * 16 + (c & 15);
        base[(cgrp * 64 + lane) * 8 + j] = (__bf16)acc[c];
    }
}

// ---------------------------------------------------------------------------
// Kernel 2: pass-1 spmm. LDS-staged contiguous NT reads, 2-tile reg prefetch,
// PER-BLOCK ROTATED tile order (decorrelates HBM channel usage across blocks),
// bf16 MFMA vs Btf; side-writes u4-packed adj fragments (A4) for pass 2.
// ---------------------------------------------------------------------------
__global__ __launch_bounds__(256, 3)
void k_spmm1(const float* __restrict__ adj, const __bf16* __restrict__ Btf,
             const float* __restrict__ b1, unsigned int* __restrict__ A4,
             __bf16* __restrict__ h1)
{
    __shared__ __align__(16) __bf16 lds[2 * 32 * BK];   // 2 x 16 KB
    const int tid  = threadIdx.x;
    const int lane = tid & 63;
    const int w    = tid >> 6;
    const int ln15 = lane & 15;
    const int kg   = lane >> 4;
    const int bx   = blockIdx.x;
    const int m    = blockIdx.y;
    const int u0   = bx * 32;

    // per-block tile rotation: all blocks start at different K offsets
    const int t0 = (bx * 5 + m * 11) & (NT - 1);

    const float*  Arow = adj + (size_t)m * NNODES * NNODES
                             + (size_t)(u0 + w * 8) * NNODES;
    const __bf16* Bb   = Btf + (size_t)m * A_KBLKS * 1024;

    f32x4 acc00 = {0.f,0.f,0.f,0.f}, acc01 = {0.f,0.f,0.f,0.f};
    f32x4 acc10 = {0.f,0.f,0.f,0.f}, acc11 = {0.f,0.f,0.f,0.f};

    f32x4 stA[8], stB[8];

    auto issue = [&](f32x4* st, int t) {
        const float* An = Arow + (size_t)t * BK;
#pragma unroll
        for (int rr = 0; rr < 8; ++rr)
            st[rr] = __builtin_nontemporal_load(
                (const f32x4*)(An + (size_t)rr * NNODES + lane * 4));
    };
    auto stage = [&](f32x4* st, int buf) {
#pragma unroll
        for (int rr = 0; rr < 8; ++rr) {
            const int row = w * 8 + rr;
            bf16x4 c4;
#pragma unroll
            for (int e = 0; e < 4; ++e) c4[e] = (__bf16)st[rr][e];
            const int idx = buf + row * BK + lane * 4;
            *(bf16x4*)(&lds[idx ^ (rr << 3)]) = c4;
        }
    };
    auto mfma_phase = [&](int buf, int t) {
#pragma unroll
        for (int kk = 0; kk < 2; ++kk) {
            const int klocal = w * 64 + kk * 32;
            const int kb     = t * 8 + w * 2 + kk;
            const int i0 = (buf + ln15 * BK + klocal + kg * 8) ^ ((ln15 & 7) << 3);
            const int i1 = (buf + (ln15 + 16) * BK + klocal + kg * 8) ^ ((ln15 & 7) << 3);
            bf16x8 a0 = *(const bf16x8*)(&lds[i0]);
            bf16x8 a1 = *(const bf16x8*)(&lds[i1]);
            bf16x8 b0 = *(const bf16x8*)(Bb + ((size_t)kb * 2 + 0) * 512 + lane * 8);
            bf16x8 b1f= *(const bf16x8*)(Bb + ((size_t)kb * 2 + 1) * 512 + lane * 8);
            acc00 = __builtin_amdgcn_mfma_f32_16x16x32_bf16(a0, b0, acc00, 0, 0, 0);
            acc01 = __builtin_amdgcn_mfma_f32_16x16x32_bf16(a0, b1f, acc01, 0, 0, 0);
            acc10 = __builtin_amdgcn_mfma_f32_16x16x32_bf16(a1, b0, acc10, 0, 0, 0);
            acc11 = __builtin_amdgcn_mfma_f32_16x16x32_bf16(a1, b1f, acc11, 0, 0, 0);

            // u4(adj*8192*15) fragment side-write for pass 2
            A4[a4_off(m, bx * 2 + 0, kb, lane) >> 2] = pack_u4(a0);
            A4[a4_off(m, bx * 2 + 1, kb, lane) >> 2] = pack_u4(a1);
        }
    };

    issue(stA, t0);
    issue(stB, (t0 + 1) & (NT - 1));

    for (int t = 0; t < NT; t += 2) {
        const int tA = (t0 + t)     & (NT - 1);
        const int tB = (t0 + t + 1) & (NT - 1);
        stage(stA, 0);
        __syncthreads();
        if (t + 2 < NT) issue(stA, (t0 + t + 2) & (NT - 1));
        mfma_phase(0, tA);

        stage(stB, 32 * BK);
        __syncthreads();
        if (t + 3 < NT) issue(stB, (t0 + t + 3) & (NT - 1));
        mfma_phase(32 * BK, tB);
    }

    __syncthreads();
    float* red = (float*)lds;
#pragma unroll
    for (int i = 0; i < 2; ++i)
#pragma unroll
        for (int j = 0; j < 2; ++j) {
            f32x4 acc = (i == 0) ? (j == 0 ? acc00 : acc01)
                                 : (j == 0 ? acc10 : acc11);
            const int c = 16 * j + ln15;
#pragma unroll
            for (int e = 0; e < 4; ++e) {
                const int u = 16 * i + 4 * kg + e;
                red[(w * 1024) + u * 32 + c] = acc[e];
            }
        }
    __syncthreads();

    {
        const int u  = tid >> 3;
        const int c0 = (tid & 7) * 4;
        f32x4 s = *(const f32x4*)(&red[u * 32 + c0]);
#pragma unroll
        for (int ww = 1; ww < 4; ++ww)
            s += *(const f32x4*)(&red[ww * 1024 + u * 32 + c0]);
        bf16x4 o4;
#pragma unroll
        for (int e = 0; e < 4; ++e) {
            float val = s[e] + b1[m * NHID + c0 + e];
            o4[e] = (__bf16)(val > 0.f ? val : 0.f);
        }
        *(bf16x4*)(h1 + ((size_t)m * NNODES + u0 + u) * NHID + c0) = o4;
    }
}

// ---------------------------------------------------------------------------
// Kernel 3: T2t8[m][d][v] = fp8(64 * (h1[m][v][:] @ W2[m]))
// ---------------------------------------------------------------------------
__global__ __launch_bounds__(256)
void k_hw(const __bf16* __restrict__ h1, const float* __restrict__ W2,
          unsigned char* __restrict__ T2t8)
{
    __shared__ float w[NHID * NHID];
    const int m = blockIdx.y, t = threadIdx.x;
    for (int idx = t; idx < NHID * NHID; idx += 256)
        w[idx] = W2[m * NHID * NHID + idx];
    __syncthreads();

    const int v = blockIdx.x * 256 + t;
    const __bf16* hr = h1 + ((size_t)m * NNODES + v) * NHID;
    float h[NHID];
#pragma unroll
    for (int i = 0; i < 4; ++i) {
        bf16x8 hb = *(const bf16x8*)(hr + i * 8);
#pragma unroll
        for (int e = 0; e < 8; ++e) h[i * 8 + e] = (float)hb[e];
    }

    float acc[NHID];
#pragma unroll
    for (int d = 0; d < NHID; ++d) acc[d] = 0.f;
    for (int hh = 0; hh < NHID; ++hh) {
        const float hs = h[hh];
#pragma unroll
        for (int d = 0; d < NHID; ++d) acc[d] += hs * w[hh * NHID + d];
    }
#pragma unroll
    for (int d = 0; d < NHID; ++d) {
        unsigned int p = __builtin_amdgcn_cvt_pk_fp8_f32(acc[d] * 64.0f, 0.f, 0u, false);
        T2t8[((size_t)m * NHID + d) * NNODES + v] = (unsigned char)(p & 0xff);
    }
}

// ---------------------------------------------------------------------------
// Kernel 4: pass-2 spmm: u4 A-frags expanded to fp8 in-register + fp8 B.
// Per-block rotated 256-k chunk order (same decorrelation mechanism).
// ---------------------------------------------------------------------------
__global__ __launch_bounds__(64)
void k_spmm2(const unsigned int* __restrict__ A4,
             const unsigned char* __restrict__ T2t8,
             float* __restrict__ h2p4)
{
    const int lane = threadIdx.x;
    const int ln15 = lane & 15;
    const int kg   = lane >> 4;
    const int bx   = blockIdx.x;
    const int kz   = blockIdx.y;
    const int m    = blockIdx.z;
    const int u0   = bx * 32;
    const int kbeg = kz * KRANGE;
    const int rot  = (bx + kz * 3 + m * 5) & 7;

    const unsigned int* A4f0 = A4 + (a4_off(m, bx * 2 + 0, 0, lane) >> 2);
    const unsigned int* A4f1 = A4 + (a4_off(m, bx * 2 + 1, 0, lane) >> 2);
    const unsigned char* B0 = T2t8 + (size_t)m * NHID * NNODES
                                   + (size_t)ln15 * NNODES + kg * 8;
    const unsigned char* B1 = B0 + (size_t)16 * NNODES;

    f32x4 acc00 = {0.f,0.f,0.f,0.f}, acc01 = {0.f,0.f,0.f,0.f};
    f32x4 acc10 = {0.f,0.f,0.f,0.f}, acc11 = {0.f,0.f,0.f,0.f};

    for (int c = 0; c < 8; ++c) {
        const int k0 = kbeg + (((c + rot) & 7) << 8);
#pragma unroll
        for (int kk = 0; kk < 8; ++kk) {
            const int k  = k0 + kk * 32;
            const int kb = k >> 5;
            unsigned int w0 = A4f0[(size_t)kb * 64];
            unsigned int w1 = A4f1[(size_t)kb * 64];
            long a0 = expand_u4(w0);
            long a1 = expand_u4(w1);
            long b0 = *(const long*)(B0 + k);
            long b1 = *(const long*)(B1 + k);
            acc00 = __builtin_amdgcn_mfma_f32_16x16x32_fp8_fp8(a0, b0, acc00, 0, 0, 0);
            acc01 = __builtin_amdgcn_mfma_f32_16x16x32_fp8_fp8(a0, b1, acc01, 0, 0, 0);
            acc10 = __builtin_amdgcn_mfma_f32_16x16x32_fp8_fp8(a1, b0, acc10, 0, 0, 0);
            acc11 = __builtin_amdgcn_mfma_f32_16x16x32_fp8_fp8(a1, b1, acc11, 0, 0, 0);
        }
    }

    const float INV = 1.0f / (122880.0f * 64.0f);   // undo u4 and fp8-B scales
    float* hp = h2p4 + (((size_t)kz * NMETA + m) * NNODES) * NHID;
#pragma unroll
    for (int i = 0; i < 2; ++i)
#pragma unroll
        for (int j = 0; j < 2; ++j) {
            f32x4 acc = (i == 0) ? (j == 0 ? acc00 : acc01)
                                 : (j == 0 ? acc10 : acc11);
            const int c = 16 * j + ln15;
#pragma unroll
            for (int e = 0; e < 4; ++e) {
                const int u = u0 + 16 * i + 4 * kg + e;
                hp[(size_t)u * NHID + c] = acc[e] * INV;
            }
        }
}

// ---------------------------------------------------------------------------
// Kernel 5a: wide reduce  h2[m][n][:] = relu(sum_kz h2p4 + b2)
// ---------------------------------------------------------------------------
__global__ __launch_bounds__(256)
void k_red(const float* __restrict__ h2p4, const float* __restrict__ b2,
           float* __restrict__ h2)
{
    const int tid = blockIdx.x * 256 + threadIdx.x;
    const int d4  = tid & 7;
    const int nm  = tid >> 3;
    const int n   = nm & (NNODES - 1);
    const int m   = nm >> 13;

    f32x4 s = {0.f,0.f,0.f,0.f};
#pragma unroll
    for (int kz = 0; kz < KSPLIT; ++kz)
        s += *(const f32x4*)(h2p4 +
            (((size_t)kz * NMETA + m) * NNODES + n) * NHID + d4 * 4);

    f32x4 o;
#pragma unroll
    for (int e = 0; e < 4; ++e) {
        float val = s[e] + b2[m * NHID + d4 * 4 + e];
        o[e] = val > 0.f ? val : 0.f;
    }
    *(f32x4*)(h2 + ((size_t)m * NNODES + n) * NHID + d4 * 4) = o;
}

// ---------------------------------------------------------------------------
// Kernel 5b: attention + linear + log_softmax  (128 blocks x 64 thr)
// ---------------------------------------------------------------------------
__global__ __launch_bounds__(64)
void k_final(const float* __restrict__ h2, const float* __restrict__ a,
             const float* __restrict__ Wl, const float* __restrict__ bl,
             float* __restrict__ out)
{
    __shared__ float ws_a[NHID];
    __shared__ float ws_w[NHID * NCLASS];
    __shared__ float ws_b[NCLASS];
    const int t = threadIdx.x;
    if (t < NHID) ws_a[t] = a[t];
    for (int idx = t; idx < NHID * NCLASS; idx += 64) ws_w[idx] = Wl[idx];
    if (t < NCLASS) ws_b[t] = bl[t];
    __syncthreads();

    const int n = blockIdx.x * 64 + t;

    float hv[NMETA][NHID];
#pragma unroll
    for (int m = 0; m < NMETA; ++m) {
        const f32x4* hp = (const f32x4*)(h2 + ((size_t)m * NNODES + n) * NHID);
#pragma unroll
        for (int d4 = 0; d4 < NHID / 4; ++d4) {
            f32x4 v = hp[d4];
#pragma unroll
            for (int e = 0; e < 4; ++e) hv[m][d4 * 4 + e] = v[e];
        }
    }

    float em[NMETA];
#pragma unroll
    for (int m = 0; m < NMETA; ++m) {
        float d = 0.f;
#pragma unroll
        for (int h = 0; h < NHID; ++h) d += hv[m][h] * ws_a[h];
        em[m] = d > 0.f ? d : ALPHA * d;
    }

    float mx = fmaxf(em[0], fmaxf(em[1], em[2]));
    float w0 = __expf(em[0] - mx), w1 = __expf(em[1] - mx), w2 = __expf(em[2] - mx);
    float inv = 1.f / (w0 + w1 + w2);
    w0 *= inv; w1 *= inv; w2 *= inv;

    float o[NHID];
#pragma unroll
    for (int d = 0; d < NHID; ++d)
        o[d] = w0 * hv[0][d] + w1 * hv[1][d] + w2 * hv[2][d];

    float lg[NCLASS];
#pragma unroll
    for (int c = 0; c < NCLASS; ++c) lg[c] = ws_b[c];
    for (int d = 0; d < NHID; ++d) {
        const float od = o[d];
#pragma unroll
        for (int c = 0; c < NCLASS; ++c) lg[c] += od * ws_w[d * NCLASS + c];
    }
#pragma unroll
    for (int c = 0; c < NCLASS; ++c) lg[c] = lg[c] > 0.f ? lg[c] : 0.f;

    float lmx = lg[0];
#pragma unroll
    for (int c = 1; c < NCLASS; ++c) lmx = fmaxf(lmx, lg[c]);
    float ls = 0.f;
#pragma unroll
    for (int c = 0; c < NCLASS; ++c) ls += __expf(lg[c] - lmx);
    const float lse = lmx + __logf(ls);
#pragma unroll
    for (int c = 0; c < NCLASS; ++c)
        out[(size_t)n * NCLASS + c] = lg[c] - lse;
}

// ---------------------------------------------------------------------------
extern "C" void kernel_launch(void* const* d_in, const int* in_sizes, int n_in,
                              void* d_out, int out_size, void* d_ws, size_t ws_size,
                              hipStream_t stream) {
    const float* x    = (const float*)d_in[0];
    const float* adjs = (const float*)d_in[1];
    const float* W1   = (const float*)d_in[2];
    const float* b1   = (const float*)d_in[3];
    const float* W2   = (const float*)d_in[4];
    const float* b2   = (const float*)d_in[5];
    const float* a    = (const float*)d_in[6];
    const float* Wl   = (const float*)d_in[7];
    const float* bl   = (const float*)d_in[8];
    float* out = (float*)d_out;

    char* ws = (char*)d_ws;
    // layout: Btf 1.5MB @0 | T2t8 0.75MB @2MB | h1 1.5MB @3MB |
    //         h2 3MB @8MB | h2p4 12.6MB @16MB | A4 100.7MB @32MB
    __bf16*        Btf  = (__bf16*)(ws);
    unsigned char* T2t8 = (unsigned char*)(ws + (2ull  << 20));
    __bf16*        h1   = (__bf16*)       (ws + (3ull  << 20));
    float*         h2   = (float*)        (ws + (8ull  << 20));
    float*         h2p4 = (float*)        (ws + (16ull << 20));
    unsigned int*  A4   = (unsigned int*) (ws + (32ull << 20));

    dim3 gsmall(NNODES / 256, NMETA);

    k_xw   <<<gsmall, 256, 0, stream>>>(x, W1, Btf);
    k_spmm1<<<dim3(NNODES / 32, NMETA), 256, 0, stream>>>(adjs, Btf, b1, A4, h1);
    k_hw   <<<gsmall, 256, 0, stream>>>(h1, W2, T2t8);
    k_spmm2<<<dim3(NNODES / 32, KSPLIT, NMETA), 64, 0, stream>>>(A4, T2t8, h2p4);
    k_red  <<<NMETA * NNODES * 8 / 256, 256, 0, stream>>>(h2p4, b2, h2);
    k_final<<<NNODES / 64, 64, 0, stream>>>(h2, a, Wl, bl, out);
}